// Round 4
// baseline (269.480 us; speedup 1.0000x reference)
//
#include <hip/hip_runtime.h>

#define B_N 8192
#define D_N 1024
#define C_N 1024
#define GRID 512
#define BM 128
#define BN 128
#define BK 64

typedef __attribute__((ext_vector_type(8))) __bf16 bf16x8;
typedef __attribute__((ext_vector_type(4))) float floatx4;

__device__ inline unsigned short f2bf(float f) {
  union { float f; unsigned int u; } cv; cv.f = f;
  unsigned int b = cv.u;
  unsigned int r = (b + 0x7FFFu + ((b >> 16) & 1u)) >> 16;  // RNE
  return (unsigned short)r;
}
__device__ inline float d4(const float4 a) {
  return a.x * a.x + a.y * a.y + a.z * a.z + a.w * a.w;
}
__device__ inline ushort4 pk4(const float4 v, const float s) {
  ushort4 u;
  u.x = f2bf(v.x * s); u.y = f2bf(v.y * s);
  u.z = f2bf(v.z * s); u.w = f2bf(v.w * s);
  return u;
}

// Device-scope two-sided grid barrier: all GRID blocks are co-resident
// (LDS 33KB -> 4 blk/CU, launch_bounds(256,3) -> VGPR<=168 -> >=3 blk/CU,
// capacity >= 768 > 512). threadfence = L2 writeback + L1 inv (agent scope).
__device__ inline void grid_barrier(int* counter) {
  __syncthreads();
  if (threadIdx.x == 0) {
    __threadfence();
    __hip_atomic_fetch_add(counter, 1, __ATOMIC_RELEASE, __HIP_MEMORY_SCOPE_AGENT);
    while (__hip_atomic_load(counter, __ATOMIC_ACQUIRE, __HIP_MEMORY_SCOPE_AGENT) < GRID)
      __builtin_amdgcn_s_sleep(1);
    __threadfence();
  }
  __syncthreads();
}

__global__ __launch_bounds__(256, 3) void fused_kernel(
    const float* __restrict__ emb_i, const float* __restrict__ emb_j,
    const int* __restrict__ labels,
    unsigned short* __restrict__ z_j, unsigned short* __restrict__ proto,
    float* __restrict__ p2, int* __restrict__ cnt, int* __restrict__ idx,
    int* __restrict__ bar, float* __restrict__ out) {
  __shared__ __align__(16) unsigned short As[BM * BK];
  __shared__ __align__(16) unsigned short Bs[BN * BK];
  __shared__ float sx[4][8];
  __shared__ float sred[4];

  const int t = threadIdx.x;
  const int lane = t & 63;
  const int wid = t >> 6;
  const int blk = blockIdx.x;

  // ---------------- Phase A: normalize emb_j -> z_j bf16; build idx --------
  if (t < 16) {
    const int row = blk * 16 + t;
    const int lab = labels[row];
    const int pos = atomicAdd(&cnt[lab], 1) & 7;  // exactly 8 per class
    idx[lab * 8 + pos] = row;
  }
#pragma unroll
  for (int r = 0; r < 4; ++r) {
    const int row = blk * 16 + wid * 4 + r;
    const float4* src = (const float4*)(emb_j + (size_t)row * D_N);
    const float4 v0 = src[lane], v1 = src[lane + 64];
    const float4 v2 = src[lane + 128], v3 = src[lane + 192];
    float ss = d4(v0) + d4(v1) + d4(v2) + d4(v3);
    for (int o = 32; o; o >>= 1) ss += __shfl_xor(ss, o, 64);
    const float inv = 1.0f / fmaxf(sqrtf(ss), 1e-12f);
    ushort4* dst = (ushort4*)(z_j + (size_t)row * D_N);
    dst[lane] = pk4(v0, inv);
    dst[lane + 64] = pk4(v1, inv);
    dst[lane + 128] = pk4(v2, inv);
    dst[lane + 192] = pk4(v3, inv);
  }

  grid_barrier(&bar[0]);

  // ---------------- Phase B: prototypes from raw emb_i ---------------------
  // 2 classes/block, one class per wave-pair, each wave owns half of D.
  {
    const int c = blk * 2 + (wid >> 1);
    const int half = wid & 1;
    const float* base = emb_i + half * 512;
    float4 v0[8], v1[8];
    float inv[8];
    {
      float ss[8];
#pragma unroll
      for (int k = 0; k < 8; ++k) {
        const int row = idx[c * 8 + k];
        const float4* src = (const float4*)(base + (size_t)row * D_N);
        v0[k] = src[lane];
        v1[k] = src[lane + 64];
        ss[k] = d4(v0[k]) + d4(v1[k]);
      }
#pragma unroll
      for (int k = 0; k < 8; ++k)
        for (int o = 32; o; o >>= 1) ss[k] += __shfl_xor(ss[k], o, 64);
      if (lane == 0) {
#pragma unroll
        for (int k = 0; k < 8; ++k) sx[wid][k] = ss[k];
      }
    }
    __syncthreads();
#pragma unroll
    for (int k = 0; k < 8; ++k) {
      const float tot = sx[wid][k] + sx[wid ^ 1][k];
      inv[k] = 1.0f / fmaxf(sqrtf(tot), 1e-12f);
    }
    float4 a0 = make_float4(0.f, 0.f, 0.f, 0.f);
    float4 a1 = make_float4(0.f, 0.f, 0.f, 0.f);
#pragma unroll
    for (int k = 0; k < 8; ++k) {
      const float iv = inv[k];
      a0.x += v0[k].x * iv; a0.y += v0[k].y * iv;
      a0.z += v0[k].z * iv; a0.w += v0[k].w * iv;
      a1.x += v1[k].x * iv; a1.y += v1[k].y * iv;
      a1.z += v1[k].z * iv; a1.w += v1[k].w * iv;
    }
    a0.x *= 0.125f; a0.y *= 0.125f; a0.z *= 0.125f; a0.w *= 0.125f;
    a1.x *= 0.125f; a1.y *= 0.125f; a1.z *= 0.125f; a1.w *= 0.125f;

    float pp = d4(a0) + d4(a1);
    for (int o = 32; o; o >>= 1) pp += __shfl_xor(pp, o, 64);
    __syncthreads();  // inv reads of sx done before reuse
    if (lane == 0) sx[wid][0] = pp;
    __syncthreads();
    if (lane == 0 && half == 0) p2[c] = sx[wid][0] + sx[wid ^ 1][0];

    ushort4* dst = (ushort4*)(proto + (size_t)c * D_N + half * 512);
    dst[lane] = pk4(a0, 1.0f);
    dst[lane + 64] = pk4(a1, 1.0f);
  }

  grid_barrier(&bar[1]);

  // ---------------- Phase C: bf16 GEMM (z_j @ proto^T) + BCE epilogue ------
  const int bm = blk & 63;
  const int bn = blk >> 6;

  floatx4 acc[4][4];
#pragma unroll
  for (int i = 0; i < 4; ++i)
#pragma unroll
    for (int j = 0; j < 4; ++j)
      acc[i][j] = (floatx4){0.f, 0.f, 0.f, 0.f};

  const int wm = (wid >> 1) * 64;
  const int wn = (wid & 1) * 64;
  // XOR-swizzled staging (verified conflict-free): slot cs=t%8 holds global
  // chunk cs^(row&7); inverse applied on ds_read side.
  const int srow = t >> 3;
  const int scol = (((t & 7) ^ (srow & 7)) << 3);
  const unsigned short* Ag = z_j + (size_t)(bm * BM + srow) * D_N + scol;
  const unsigned short* Bg = proto + (size_t)(bn * BN + srow) * D_N + scol;
  unsigned short* Al = As + t * 8;
  unsigned short* Bl = Bs + t * 8;

  for (int k0 = 0; k0 < D_N; k0 += BK) {
#pragma unroll
    for (int it = 0; it < 4; ++it) {
      __builtin_amdgcn_global_load_lds(
          (const __attribute__((address_space(1))) void*)(Ag + (size_t)it * 32 * D_N + k0),
          (__attribute__((address_space(3))) void*)(Al + it * 2048), 16, 0, 0);
      __builtin_amdgcn_global_load_lds(
          (const __attribute__((address_space(1))) void*)(Bg + (size_t)it * 32 * D_N + k0),
          (__attribute__((address_space(3))) void*)(Bl + it * 2048), 16, 0, 0);
    }
    __syncthreads();
#pragma unroll
    for (int kk = 0; kk < BK; kk += 32) {
      const int swz = ((((kk >> 3) + (lane >> 4)) ^ (lane & 7)) << 3);
      bf16x8 af[4], bfr[4];
#pragma unroll
      for (int mi = 0; mi < 4; ++mi)
        af[mi] = *(const bf16x8*)(As + (wm + mi * 16 + (lane & 15)) * BK + swz);
#pragma unroll
      for (int ni = 0; ni < 4; ++ni)
        bfr[ni] = *(const bf16x8*)(Bs + (wn + ni * 16 + (lane & 15)) * BK + swz);
#pragma unroll
      for (int mi = 0; mi < 4; ++mi)
#pragma unroll
        for (int ni = 0; ni < 4; ++ni)
          acc[mi][ni] = __builtin_amdgcn_mfma_f32_16x16x32_bf16(af[mi], bfr[ni], acc[mi][ni], 0, 0, 0);
    }
    __syncthreads();
  }

  // epilogue: C/D layout col=lane&15, row=(lane>>4)*4+reg
  const int colb = bn * BN + wn + (lane & 15);
  const int rowb = bm * BM + wm + ((lane >> 4) << 2);
  float p2c[4];
#pragma unroll
  for (int ni = 0; ni < 4; ++ni) p2c[ni] = p2[colb + ni * 16];

  float lsum = 0.f;
#pragma unroll
  for (int mi = 0; mi < 4; ++mi) {
#pragma unroll
    for (int r = 0; r < 4; ++r) {
      const int row = rowb + mi * 16 + r;
      const int lab = labels[row];
#pragma unroll
      for (int ni = 0; ni < 4; ++ni) {
        const float dot = acc[mi][ni][r];
        const float d2 = 1.0f + p2c[ni] - 2.0f * dot;
        const float s = 2.0f - sqrtf(fmaxf(d2, 0.0f));
        const float sp = fmaxf(s, 0.0f) + log1pf(expf(-fabsf(s)));
        lsum += sp - ((lab == colb + ni * 16) ? s : 0.0f);
      }
    }
  }
  for (int o = 32; o; o >>= 1) lsum += __shfl_xor(lsum, o, 64);
  if (lane == 0) sred[wid] = lsum;
  __syncthreads();
  if (t == 0)
    atomicAdd(out, (sred[0] + sred[1] + sred[2] + sred[3]) *
                       (1.0f / ((float)B_N * (float)C_N)));
}

// ---------------------------------------------------------------------------
extern "C" void kernel_launch(void* const* d_in, const int* in_sizes, int n_in,
                              void* d_out, int out_size, void* d_ws, size_t ws_size,
                              hipStream_t stream) {
  const float* emb_i = (const float*)d_in[0];
  const float* emb_j = (const float*)d_in[1];
  const int* labels = (const int*)d_in[2];
  float* out = (float*)d_out;

  char* ws = (char*)d_ws;
  unsigned short* z_j = (unsigned short*)ws;                         // 16 MB
  unsigned short* proto = (unsigned short*)(ws + (size_t)16777216);  // 2 MB
  float* p2 = (float*)(ws + (size_t)18874368);                       // 4 KB
  int* cnt = (int*)(ws + (size_t)18878464);                          // 4 KB
  int* idx = (int*)(ws + (size_t)18882560);                          // 32 KB
  int* bar = (int*)(ws + (size_t)18915328);                          // 8 B

  hipMemsetAsync(cnt, 0, C_N * sizeof(int), stream);
  hipMemsetAsync(bar, 0, 2 * sizeof(int), stream);
  hipMemsetAsync(out, 0, sizeof(float), stream);
  fused_kernel<<<dim3(GRID), 256, 0, stream>>>(emb_i, emb_j, labels, z_j,
                                               proto, p2, cnt, idx, bar, out);
}